// Round 2
// baseline (1103.519 us; speedup 1.0000x reference)
//
#include <hip/hip_runtime.h>
#include <hip/hip_bf16.h>

#define HID 512
#define ENCD 512
#define NB 256
#define SEQ 1024
#define LDSTR 520   // ushorts per LDS row (512 + 8 pad, keeps 16B alignment)

typedef short bf16x8 __attribute__((ext_vector_type(8)));
typedef float floatx4 __attribute__((ext_vector_type(4)));
typedef unsigned short ushort8v __attribute__((ext_vector_type(8)));

__device__ __forceinline__ unsigned short f2bf(float f) {
    unsigned u = __builtin_bit_cast(unsigned, f);
    u += 0x7FFFu + ((u >> 16) & 1u);   // round-to-nearest-even
    return (unsigned short)(u >> 16);
}
__device__ __forceinline__ ushort4 cvt4(float4 a) {
    return make_ushort4(f2bf(a.x), f2bf(a.y), f2bf(a.z), f2bf(a.w));
}
__device__ __forceinline__ ushort8v cvt8(float4 a, float4 b) {
    ushort8v r;
    r[0]=f2bf(a.x); r[1]=f2bf(a.y); r[2]=f2bf(a.z); r[3]=f2bf(a.w);
    r[4]=f2bf(b.x); r[5]=f2bf(b.y); r[6]=f2bf(b.z); r[7]=f2bf(b.w);
    return r;
}

// ---------------------------------------------------------------------------
// Kernel 1: B-shuffle (W_s -> fragment-major bf16) + proj_h = dh @ W_h^T
// (unchanged — verified)
// ---------------------------------------------------------------------------
__global__ __launch_bounds__(256) void prep_kernel(
    const float* __restrict__ dh,      // [256][512]
    const float* __restrict__ W_h,     // [512][512]
    const float* __restrict__ W_s,     // [512][512]
    float* __restrict__ proj_h,        // [256][512]
    unsigned short* __restrict__ Bshuf)// [32768][8] bf16
{
    __shared__ float sdh[2][HID];
    const int blk = blockIdx.x;
    const int t = threadIdx.x;
    const int b0 = blk * 2;

    ((float4*)&sdh[0][0])[t] = ((const float4*)(dh + (size_t)b0 * HID))[t];

    {
        const int id   = blk * 256 + t;
        const int lane = id & 63;
        const int nj   = (id >> 6) & 7;
        const int kt   = (id >> 9) & 15;
        const int wnG  = id >> 13;
        const int n = wnG * 128 + nj * 16 + (lane & 15);
        const int k = kt * 32 + (lane >> 4) * 8;
        const float* src = W_s + (size_t)n * HID + k;
        float4 s0 = *(const float4*)src;
        float4 s1 = *(const float4*)(src + 4);
        *(ushort4*)(Bshuf + (size_t)id * 8)     = cvt4(s0);
        *(ushort4*)(Bshuf + (size_t)id * 8 + 4) = cvt4(s1);
    }
    __syncthreads();

    #pragma unroll
    for (int i = 0; i < 2; ++i) {
        const int h = t + i * 256;
        const float4* wr = (const float4*)(W_h + (size_t)h * HID);
        float acc0 = 0.f, acc1 = 0.f;
        #pragma unroll 8
        for (int e4 = 0; e4 < HID / 4; ++e4) {
            float4 w  = wr[e4];
            float4 s0 = ((const float4*)&sdh[0][0])[e4];
            float4 s1 = ((const float4*)&sdh[1][0])[e4];
            acc0 += w.x * s0.x + w.y * s0.y + w.z * s0.z + w.w * s0.w;
            acc1 += w.x * s1.x + w.y * s1.y + w.z * s1.z + w.w * s1.w;
        }
        proj_h[(size_t)b0 * HID + h]       = acc0;
        proj_h[(size_t)(b0 + 1) * HID + h] = acc1;
    }
}

// ---------------------------------------------------------------------------
// Kernel 2: FUSED score-GEMM + online-softmax + context.
// One block per batch (256 blocks, 1/CU, 512 threads = 8 waves).
// Per 64-row half-tile: stage enc->LDS bf16 (dbuf), GEMM (no per-K barrier,
// whole K resident), tanh+v-dot epilogue, online softmax (wave 0), context
// C = C*r + sum(e * enc_fp32)  (global re-read, L2-hot).
// enc is read from HBM exactly once (staging); everything else is L2.
// ---------------------------------------------------------------------------
__global__ __launch_bounds__(512, 2) void fused_attn(
    const float* __restrict__ enc,            // [256][1024][512] fp32
    const unsigned short* __restrict__ Bshuf, // fragment-major bf16 W_s
    const float* __restrict__ proj_h,         // [256][512]
    const float* __restrict__ v,              // [512]
    float* __restrict__ ctx_out,              // [256][512]
    float* __restrict__ alpha_out)            // [256][1024]
{
    __shared__ __align__(16) unsigned short sE[2][64 * LDSTR]; // 133 KB
    __shared__ float sred[8][64];
    __shared__ float sscore[SEQ];
    __shared__ float se[64];
    __shared__ float sconst[4];   // 0: run_m, 1: run_s, 2: rescale r

    const int t    = threadIdx.x;
    const int w    = t >> 6;
    const int lane = t & 63;
    const int ln15 = lane & 15;
    const int lk   = lane >> 4;
    const int b    = blockIdx.x;

    if (t == 0) { sconst[0] = -3.0e38f; sconst[1] = 0.f; }

    // hoisted per-wave epilogue constants (N-slice fixed per wave: w*64..+63)
    float phv[4], vv[4];
    #pragma unroll
    for (int nj = 0; nj < 4; ++nj) {
        const int n = w * 64 + nj * 16 + ln15;
        phv[nj] = proj_h[b * HID + n];
        vv[nj]  = v[n];
    }

    // B fragment base: same verified Bshuf layout, remapped for wave-N=64:
    // global n-tile J = w*4+nj -> group (w>>1), nj_offset (w&1)*4
    const unsigned short* bb0 = Bshuf + ((size_t)(w >> 1) * 8192 + lane) * 8;
    const int njo0 = (w & 1) * 4;

    const float* encB = enc + (size_t)b * SEQ * ENCD;

    // ---- prologue: stage half-tile 0 into sE[0]
    {
        const float* g = encB + (size_t)w * ENCD + lane * 8;
        float4 f[16];
        #pragma unroll
        for (int p = 0; p < 8; ++p) {
            f[2*p]   = *(const float4*)(g + (size_t)p * 8 * ENCD);
            f[2*p+1] = *(const float4*)(g + (size_t)p * 8 * ENCD + 4);
        }
        #pragma unroll
        for (int p = 0; p < 8; ++p)
            *(ushort8v*)&sE[0][(p * 8 + w) * LDSTR + lane * 8] = cvt8(f[2*p], f[2*p+1]);
    }
    float C[8] = {0.f,0.f,0.f,0.f,0.f,0.f,0.f,0.f};
    __syncthreads();

    for (int ht = 0; ht < 16; ++ht) {
        const int cur = ht & 1;
        const unsigned short* sA = &sE[cur][0];
        floatx4 acc[4][4] = {};

        bf16x8 bfA[4], bfB[4];
        #pragma unroll
        for (int nj = 0; nj < 4; ++nj)
            bfA[nj] = *(const bf16x8*)(bb0 + (size_t)(njo0 + nj) * 512);

        float4 sf[16];  // next-half-tile staging registers

        #pragma unroll
        for (int kt2 = 0; kt2 < 8; ++kt2) {
            const int kt = kt2 * 2;
            // prefetch B(kt+1)
            #pragma unroll
            for (int nj = 0; nj < 4; ++nj)
                bfB[nj] = *(const bf16x8*)(bb0 + (size_t)((kt + 1) * 8 + njo0 + nj) * 512);
            // issue next-half-tile stage loads once, early enough that the
            // next B-load vmcnt gate lands ~950cy later (HBM latency hidden)
            if (kt == 2 && ht < 15) {
                const float* gn = encB + (size_t)((ht + 1) * 64 + w) * ENCD + lane * 8;
                #pragma unroll
                for (int p = 0; p < 8; ++p) {
                    sf[2*p]   = *(const float4*)(gn + (size_t)p * 8 * ENCD);
                    sf[2*p+1] = *(const float4*)(gn + (size_t)p * 8 * ENCD + 4);
                }
            }
            {
                bf16x8 af[4];
                #pragma unroll
                for (int mi = 0; mi < 4; ++mi)
                    af[mi] = *(const bf16x8*)(&sA[(mi * 16 + ln15) * LDSTR + kt * 32 + lk * 8]);
                #pragma unroll
                for (int nj = 0; nj < 4; ++nj)
                    #pragma unroll
                    for (int mi = 0; mi < 4; ++mi)
                        acc[mi][nj] = __builtin_amdgcn_mfma_f32_16x16x32_bf16(
                            af[mi], bfA[nj], acc[mi][nj], 0, 0, 0);
            }
            if (kt + 2 < 16) {
                #pragma unroll
                for (int nj = 0; nj < 4; ++nj)
                    bfA[nj] = *(const bf16x8*)(bb0 + (size_t)((kt + 2) * 8 + njo0 + nj) * 512);
            }
            {
                bf16x8 af[4];
                #pragma unroll
                for (int mi = 0; mi < 4; ++mi)
                    af[mi] = *(const bf16x8*)(&sA[(mi * 16 + ln15) * LDSTR + (kt + 1) * 32 + lk * 8]);
                #pragma unroll
                for (int nj = 0; nj < 4; ++nj)
                    #pragma unroll
                    for (int mi = 0; mi < 4; ++mi)
                        acc[mi][nj] = __builtin_amdgcn_mfma_f32_16x16x32_bf16(
                            af[mi], bfB[nj], acc[mi][nj], 0, 0, 0);
            }
        }

        // stage next half-tile into the other buffer (writes drain during
        // epilogue VALU; visible after the epilogue barrier)
        if (ht < 15) {
            #pragma unroll
            for (int p = 0; p < 8; ++p)
                *(ushort8v*)&sE[1 - cur][(p * 8 + w) * LDSTR + lane * 8] = cvt8(sf[2*p], sf[2*p+1]);
        }

        // epilogue: tanh + v-dot, reduce over the 16 ln15 columns
        #pragma unroll
        for (int mi = 0; mi < 4; ++mi) {
            #pragma unroll
            for (int r = 0; r < 4; ++r) {
                float s = 0.f;
                #pragma unroll
                for (int nj = 0; nj < 4; ++nj) {
                    float x = acc[mi][nj][r] + phv[nj];
                    float e = __expf(2.f * x);
                    s += vv[nj] * (1.f - 2.f / (e + 1.f));   // tanh, saturation-safe
                }
                s += __shfl_xor(s, 8, 64);
                s += __shfl_xor(s, 4, 64);
                s += __shfl_xor(s, 2, 64);
                s += __shfl_xor(s, 1, 64);
                if (ln15 == 0) sred[w][mi * 16 + lk * 4 + r] = s;
            }
        }
        __syncthreads();

        // online softmax update (wave 0 only)
        if (w == 0) {
            float sc = 0.f;
            #pragma unroll
            for (int g = 0; g < 8; ++g) sc += sred[g][lane];
            sscore[ht * 64 + lane] = sc;
            float mx = sc;
            #pragma unroll
            for (int m = 32; m >= 1; m >>= 1) mx = fmaxf(mx, __shfl_xor(mx, m, 64));
            const float m_old = sconst[0];
            const float m_new = fmaxf(m_old, mx);
            const float rr    = __expf(m_old - m_new);   // 0 on first tile
            const float e     = __expf(sc - m_new);
            se[lane] = e;
            float es = e;
            #pragma unroll
            for (int m = 32; m >= 1; m >>= 1) es += __shfl_xor(es, m, 64);
            if (lane == 0) {
                sconst[0] = m_new;
                sconst[1] = sconst[1] * rr + es;
                sconst[2] = rr;
            }
        }
        __syncthreads();

        // context accumulation: fp32 enc re-read (rows just staged -> L2-hot)
        const float rr = sconst[2];
        #pragma unroll
        for (int j = 0; j < 8; ++j) C[j] *= rr;
        const float* gc = encB + (size_t)(ht * 64 + w) * ENCD + lane * 8;
        #pragma unroll
        for (int i = 0; i < 8; ++i) {
            const float ee = se[w + 8 * i];
            float4 u0 = *(const float4*)(gc + (size_t)i * 8 * ENCD);
            float4 u1 = *(const float4*)(gc + (size_t)i * 8 * ENCD + 4);
            C[0] += ee * u0.x; C[1] += ee * u0.y; C[2] += ee * u0.z; C[3] += ee * u0.w;
            C[4] += ee * u1.x; C[5] += ee * u1.y; C[6] += ee * u1.z; C[7] += ee * u1.w;
        }
    }

    // final reduce of C across waves (overlay on sE[0] — no readers remain)
    {
        float* sctx = (float*)&sE[0][0];
        *(float4*)&sctx[w * 512 + lane * 8]     = make_float4(C[0], C[1], C[2], C[3]);
        *(float4*)&sctx[w * 512 + lane * 8 + 4] = make_float4(C[4], C[5], C[6], C[7]);
    }
    __syncthreads();
    {
        const float inv = 1.f / sconst[1];
        const float m_f = sconst[0];
        const float* sctx = (const float*)&sE[0][0];
        float ssum = 0.f;
        #pragma unroll
        for (int g = 0; g < 8; ++g) ssum += sctx[g * 512 + t];
        ctx_out[(size_t)b * HID + t] = ssum * inv;
        #pragma unroll
        for (int q = 0; q < 2; ++q) {
            const int l = q * 512 + t;
            alpha_out[(size_t)b * SEQ + l] = __expf(sscore[l] - m_f) * inv;
        }
    }
}

// ---------------------------------------------------------------------------
extern "C" void kernel_launch(void* const* d_in, const int* in_sizes, int n_in,
                              void* d_out, int out_size, void* d_ws, size_t ws_size,
                              hipStream_t stream) {
    const float* dh  = (const float*)d_in[0];  // decoder_hidden [256][512]
    const float* enc = (const float*)d_in[1];  // encoder_outputs [256][1024][512]
    const float* W_h = (const float*)d_in[2];  // [512][512]
    const float* W_s = (const float*)d_in[3];  // [512][512]
    const float* v   = (const float*)d_in[4];  // [1][512]

    float* ws = (float*)d_ws;
    float* proj_h = ws;                                   // 131072 floats
    unsigned short* Bshuf = (unsigned short*)(ws + 131072); // 262144 bf16

    float* ctx   = (float*)d_out;              // [256][512]
    float* alpha = (float*)d_out + NB * HID;   // [256][1024]

    prep_kernel<<<128, 256, 0, stream>>>(dh, W_h, W_s, proj_h, Bshuf);
    fused_attn<<<NB, 512, 0, stream>>>(enc, Bshuf, proj_h, v, ctx, alpha);
}

// Round 3
// 1020.434 us; speedup vs baseline: 1.0814x; 1.0814x over previous
//
#include <hip/hip_runtime.h>
#include <hip/hip_bf16.h>

#define HID 512
#define ENCD 512
#define NB 256
#define SEQ 1024
#define LDSTR 520   // ushorts per LDS row (512 + 8 pad, keeps 16B alignment)

typedef short bf16x8 __attribute__((ext_vector_type(8)));
typedef float floatx4 __attribute__((ext_vector_type(4)));
typedef unsigned short ushort8v __attribute__((ext_vector_type(8)));

__device__ __forceinline__ unsigned short f2bf(float f) {
    unsigned u = __builtin_bit_cast(unsigned, f);
    u += 0x7FFFu + ((u >> 16) & 1u);   // round-to-nearest-even
    return (unsigned short)(u >> 16);
}
__device__ __forceinline__ ushort4 cvt4(float4 a) {
    return make_ushort4(f2bf(a.x), f2bf(a.y), f2bf(a.z), f2bf(a.w));
}
__device__ __forceinline__ ushort8v cvt8(float4 a, float4 b) {
    ushort8v r;
    r[0]=f2bf(a.x); r[1]=f2bf(a.y); r[2]=f2bf(a.z); r[3]=f2bf(a.w);
    r[4]=f2bf(b.x); r[5]=f2bf(b.y); r[6]=f2bf(b.z); r[7]=f2bf(b.w);
    return r;
}
__device__ __forceinline__ float bflo(unsigned u) {
    return __builtin_bit_cast(float, u << 16);
}
__device__ __forceinline__ float bfhi(unsigned u) {
    return __builtin_bit_cast(float, u & 0xffff0000u);
}

// ---------------------------------------------------------------------------
// Kernel 1: B-shuffle (W_s -> fragment-major bf16) + proj_h = dh @ W_h^T
// (unchanged — verified)
// ---------------------------------------------------------------------------
__global__ __launch_bounds__(256) void prep_kernel(
    const float* __restrict__ dh,      // [256][512]
    const float* __restrict__ W_h,     // [512][512]
    const float* __restrict__ W_s,     // [512][512]
    float* __restrict__ proj_h,        // [256][512]
    unsigned short* __restrict__ Bshuf)// [32768][8] bf16
{
    __shared__ float sdh[2][HID];
    const int blk = blockIdx.x;
    const int t = threadIdx.x;
    const int b0 = blk * 2;

    ((float4*)&sdh[0][0])[t] = ((const float4*)(dh + (size_t)b0 * HID))[t];

    {
        const int id   = blk * 256 + t;
        const int lane = id & 63;
        const int nj   = (id >> 6) & 7;
        const int kt   = (id >> 9) & 15;
        const int wnG  = id >> 13;
        const int n = wnG * 128 + nj * 16 + (lane & 15);
        const int k = kt * 32 + (lane >> 4) * 8;
        const float* src = W_s + (size_t)n * HID + k;
        float4 s0 = *(const float4*)src;
        float4 s1 = *(const float4*)(src + 4);
        *(ushort4*)(Bshuf + (size_t)id * 8)     = cvt4(s0);
        *(ushort4*)(Bshuf + (size_t)id * 8 + 4) = cvt4(s1);
    }
    __syncthreads();

    #pragma unroll
    for (int i = 0; i < 2; ++i) {
        const int h = t + i * 256;
        const float4* wr = (const float4*)(W_h + (size_t)h * HID);
        float acc0 = 0.f, acc1 = 0.f;
        #pragma unroll 8
        for (int e4 = 0; e4 < HID / 4; ++e4) {
            float4 w  = wr[e4];
            float4 s0 = ((const float4*)&sdh[0][0])[e4];
            float4 s1 = ((const float4*)&sdh[1][0])[e4];
            acc0 += w.x * s0.x + w.y * s0.y + w.z * s0.z + w.w * s0.w;
            acc1 += w.x * s1.x + w.y * s1.y + w.z * s1.z + w.w * s1.w;
        }
        proj_h[(size_t)b0 * HID + h]       = acc0;
        proj_h[(size_t)(b0 + 1) * HID + h] = acc1;
    }
}

// ---------------------------------------------------------------------------
// Kernel 2: FUSED score-GEMM + online-softmax + context.
// One block per batch (256 blocks, 1/CU, 512 threads = 8 waves).
// Changes vs prev round:
//  - context reads the staged bf16 LDS tile (no fp32 global re-read: that
//    was 0.4 GB of HBM L2-miss traffic + exposed dependent latency)
//  - A staging split into 4 chunks of 16 VGPRs (issue early / write late,
//    ~4 kt covering window each; compiler can't sink a 16-reg chunk)
//  - B fragments: 4-deep static register pipeline (L2 latency covered)
// ---------------------------------------------------------------------------
__global__ __launch_bounds__(512, 2) void fused_attn(
    const float* __restrict__ enc,            // [256][1024][512] fp32
    const unsigned short* __restrict__ Bshuf, // fragment-major bf16 W_s
    const float* __restrict__ proj_h,         // [256][512]
    const float* __restrict__ v,              // [512]
    float* __restrict__ ctx_out,              // [256][512]
    float* __restrict__ alpha_out)            // [256][1024]
{
    __shared__ __align__(16) unsigned short sE[2][64 * LDSTR]; // 133 KB
    __shared__ float sred[8][64];
    __shared__ float sscore[SEQ];
    __shared__ float se[64];
    __shared__ float sconst[4];   // 0: run_m, 1: run_s, 2: rescale r

    const int t    = threadIdx.x;
    const int w    = t >> 6;
    const int lane = t & 63;
    const int ln15 = lane & 15;
    const int lk   = lane >> 4;
    const int b    = blockIdx.x;

    if (t == 0) { sconst[0] = -3.0e38f; sconst[1] = 0.f; }

    // hoisted per-wave epilogue constants (N-slice fixed per wave: w*64..+63)
    float phv[4], vv[4];
    #pragma unroll
    for (int nj = 0; nj < 4; ++nj) {
        const int n = w * 64 + nj * 16 + ln15;
        phv[nj] = proj_h[b * HID + n];
        vv[nj]  = v[n];
    }

    // B fragment base: verified Bshuf layout, wave-N=64 remap:
    // global n-tile J = w*4+nj -> group (w>>1), nj_offset (w&1)*4
    const unsigned short* bb0 = Bshuf + ((size_t)(w >> 1) * 8192 + lane) * 8;
    const int njo0 = (w & 1) * 4;

    const float* encB = enc + (size_t)b * SEQ * ENCD;

    // ---- prologue: stage half-tile 0 into sE[0] (4 chunks of 2 rows)
    #pragma unroll
    for (int j = 0; j < 4; ++j) {
        const float* g0 = encB + (size_t)((2 * j) * 8 + w) * ENCD + lane * 8;
        const float* g1 = encB + (size_t)((2 * j + 1) * 8 + w) * ENCD + lane * 8;
        float4 a0 = ((const float4*)g0)[0], a1 = ((const float4*)g0)[1];
        float4 b0 = ((const float4*)g1)[0], b1 = ((const float4*)g1)[1];
        *(ushort8v*)&sE[0][((2 * j) * 8 + w) * LDSTR + lane * 8]     = cvt8(a0, a1);
        *(ushort8v*)&sE[0][((2 * j + 1) * 8 + w) * LDSTR + lane * 8] = cvt8(b0, b1);
    }
    float C[8] = {0.f,0.f,0.f,0.f,0.f,0.f,0.f,0.f};
    __syncthreads();

    for (int ht = 0; ht < 16; ++ht) {
        const int cur = ht & 1;
        const unsigned short* sA = &sE[cur][0];
        unsigned short* sW = &sE[1 - cur][0];
        floatx4 acc[4][4] = {};

        // B: preload slots for kt = 0..3 (16 x 16B from L2, overlapped)
        bf16x8 bq[4][4];
        #pragma unroll
        for (int s = 0; s < 4; ++s)
            #pragma unroll
            for (int nj = 0; nj < 4; ++nj)
                bq[s][nj] = *(const bf16x8*)(bb0 + (size_t)(s * 8 + njo0 + nj) * 512);

        // A staging chunk 0 for tile ht+1 (rows p=0,1): issue now
        const bool pf = (ht < 15);
        const float* gn = encB + (size_t)((ht + 1) * 64 + w) * ENCD + lane * 8;
        float4 s0a, s0b, s1a, s1b;
        if (pf) {
            s0a = ((const float4*)gn)[0];
            s0b = ((const float4*)gn)[1];
            s1a = ((const float4*)(gn + (size_t)8 * ENCD))[0];
            s1b = ((const float4*)(gn + (size_t)8 * ENCD))[1];
        }

        #pragma unroll
        for (int kt = 0; kt < 16; ++kt) {
            // staging events at kt=3,7,11,15: write chunk kt>>2, issue next
            if (pf && (kt & 3) == 3) {
                const int j = kt >> 2;   // chunk rows p = 2j, 2j+1
                *(ushort8v*)&sW[((2 * j) * 8 + w) * LDSTR + lane * 8]     = cvt8(s0a, s0b);
                *(ushort8v*)&sW[((2 * j + 1) * 8 + w) * LDSTR + lane * 8] = cvt8(s1a, s1b);
                if (j < 3) {
                    const float* gj = gn + (size_t)(2 * (j + 1)) * 8 * ENCD;
                    s0a = ((const float4*)gj)[0];
                    s0b = ((const float4*)gj)[1];
                    s1a = ((const float4*)(gj + (size_t)8 * ENCD))[0];
                    s1b = ((const float4*)(gj + (size_t)8 * ENCD))[1];
                }
            }

            // A fragments (LDS, conflict-free via LDSTR pad)
            bf16x8 af[4];
            #pragma unroll
            for (int mi = 0; mi < 4; ++mi)
                af[mi] = *(const bf16x8*)(&sA[(mi * 16 + ln15) * LDSTR + kt * 32 + lk * 8]);

            #pragma unroll
            for (int nj = 0; nj < 4; ++nj)
                #pragma unroll
                for (int mi = 0; mi < 4; ++mi)
                    acc[mi][nj] = __builtin_amdgcn_mfma_f32_16x16x32_bf16(
                        af[mi], bq[kt & 3][nj], acc[mi][nj], 0, 0, 0);

            // reload this slot with B(kt+4) — after use, 4-deep pipeline
            if (kt + 4 < 16) {
                #pragma unroll
                for (int nj = 0; nj < 4; ++nj)
                    bq[kt & 3][nj] = *(const bf16x8*)(bb0 + (size_t)((kt + 4) * 8 + njo0 + nj) * 512);
            }
        }

        // epilogue: tanh + v-dot, reduce over the 16 ln15 columns
        #pragma unroll
        for (int mi = 0; mi < 4; ++mi) {
            #pragma unroll
            for (int r = 0; r < 4; ++r) {
                float s = 0.f;
                #pragma unroll
                for (int nj = 0; nj < 4; ++nj) {
                    float x = acc[mi][nj][r] + phv[nj];
                    float e = __expf(2.f * x);
                    s += vv[nj] * (1.f - 2.f / (e + 1.f));   // tanh, saturation-safe
                }
                s += __shfl_xor(s, 8, 64);
                s += __shfl_xor(s, 4, 64);
                s += __shfl_xor(s, 2, 64);
                s += __shfl_xor(s, 1, 64);
                if (ln15 == 0) sred[w][mi * 16 + lk * 4 + r] = s;
            }
        }
        __syncthreads();   // publishes sred AND staged tile ht+1

        // online softmax update (wave 0 only)
        if (w == 0) {
            float sc = 0.f;
            #pragma unroll
            for (int g = 0; g < 8; ++g) sc += sred[g][lane];
            sscore[ht * 64 + lane] = sc;
            float mx = sc;
            #pragma unroll
            for (int m = 32; m >= 1; m >>= 1) mx = fmaxf(mx, __shfl_xor(mx, m, 64));
            const float m_old = sconst[0];
            const float m_new = fmaxf(m_old, mx);
            const float rr    = __expf(m_old - m_new);   // 0 on first tile
            const float e     = __expf(sc - m_new);
            se[lane] = e;
            float es = e;
            #pragma unroll
            for (int m = 32; m >= 1; m >>= 1) es += __shfl_xor(es, m, 64);
            if (lane == 0) {
                sconst[0] = m_new;
                sconst[1] = sconst[1] * rr + es;
                sconst[2] = rr;
            }
        }
        __syncthreads();

        // context accumulation from the staged bf16 LDS tile (no global read)
        {
            const float rr = sconst[2];
            #pragma unroll
            for (int j = 0; j < 8; ++j) C[j] *= rr;
            #pragma unroll
            for (int i = 0; i < 8; ++i) {
                const int r = w + 8 * i;
                const float ee = se[r];
                uint4 u = *(const uint4*)&sA[r * LDSTR + lane * 8];
                C[0] += ee * bflo(u.x); C[1] += ee * bfhi(u.x);
                C[2] += ee * bflo(u.y); C[3] += ee * bfhi(u.y);
                C[4] += ee * bflo(u.z); C[5] += ee * bfhi(u.z);
                C[6] += ee * bflo(u.w); C[7] += ee * bfhi(u.w);
            }
        }
        __syncthreads();   // context reads done before next ht stages into sA
    }

    // final reduce of C across waves (overlay on sE — no readers remain)
    {
        float* sctx = (float*)&sE[0][0];
        *(float4*)&sctx[w * 512 + lane * 8]     = make_float4(C[0], C[1], C[2], C[3]);
        *(float4*)&sctx[w * 512 + lane * 8 + 4] = make_float4(C[4], C[5], C[6], C[7]);
    }
    __syncthreads();
    {
        const float inv = 1.f / sconst[1];
        const float m_f = sconst[0];
        const float* sctx = (const float*)&sE[0][0];
        float ssum = 0.f;
        #pragma unroll
        for (int g = 0; g < 8; ++g) ssum += sctx[g * 512 + t];
        ctx_out[(size_t)b * HID + t] = ssum * inv;
        #pragma unroll
        for (int q = 0; q < 2; ++q) {
            const int l = q * 512 + t;
            alpha_out[(size_t)b * SEQ + l] = __expf(sscore[l] - m_f) * inv;
        }
    }
}

// ---------------------------------------------------------------------------
extern "C" void kernel_launch(void* const* d_in, const int* in_sizes, int n_in,
                              void* d_out, int out_size, void* d_ws, size_t ws_size,
                              hipStream_t stream) {
    const float* dh  = (const float*)d_in[0];  // decoder_hidden [256][512]
    const float* enc = (const float*)d_in[1];  // encoder_outputs [256][1024][512]
    const float* W_h = (const float*)d_in[2];  // [512][512]
    const float* W_s = (const float*)d_in[3];  // [512][512]
    const float* v   = (const float*)d_in[4];  // [1][512]

    float* ws = (float*)d_ws;
    float* proj_h = ws;                                   // 131072 floats
    unsigned short* Bshuf = (unsigned short*)(ws + 131072); // 262144 bf16

    float* ctx   = (float*)d_out;              // [256][512]
    float* alpha = (float*)d_out + NB * HID;   // [256][1024]

    prep_kernel<<<128, 256, 0, stream>>>(dh, W_h, W_s, proj_h, Bshuf);
    fused_attn<<<NB, 512, 0, stream>>>(enc, Bshuf, proj_h, v, ctx, alpha);
}